// Round 7
// baseline (863.842 us; speedup 1.0000x reference)
//
#include <hip/hip_runtime.h>
#include <hip/hip_bf16.h>
#include <math.h>

#define H 768
#define B 256
#define T 100
#define G4 3072   // 4*H

typedef __attribute__((ext_vector_type(8))) short short8;
typedef __attribute__((ext_vector_type(4))) float f32x4;
typedef unsigned long long u64;

static __device__ __forceinline__ float sigm(float x) {
    return 1.0f / (1.0f + __expf(-x));
}
static __device__ __forceinline__ float tanh_fast(float x) {
    return 1.0f - 2.0f / (__expf(2.0f * x) + 1.0f);
}

// ---------------- fused prep (single dispatch) ----------------
// grid dim3(3, 3508), block 256:
//   y <  3072 : weights row y
//   y <  3152 : Wp row (y-3072), zero-padded beyond 72
//   y <  3408 : A0/batch row (y-3152)
//   y <  3508 : flags chunk (y-3408), bx==0 only
__global__ void prep_all(const float* __restrict__ src, const float* __restrict__ h0,
                         const float* __restrict__ Wih, const float* __restrict__ Whh,
                         const float* __restrict__ bih, const float* __restrict__ bhh,
                         const float* __restrict__ Wpost,
                         __hip_bfloat16* __restrict__ Wc,    // 3072 x 768 (Wih+Whh)
                         __hip_bfloat16* __restrict__ Wcat,  // 3072 x 1536 [Wih|Whh]
                         float* __restrict__ bias,           // 3072
                         __hip_bfloat16* __restrict__ Wp,    // 80 x 768
                         __hip_bfloat16* __restrict__ A0,    // 256 x 1536 [x0|h0]
                         unsigned* __restrict__ flags)       // 100*16*16, zeroed
{
    const int bx = blockIdx.x;
    const int y  = blockIdx.y;
    const int k  = bx * 256 + threadIdx.x;
    if (y < 3072) {
        float a = Wih[y * H + k];
        float b = Whh[y * H + k];
        Wc[y * H + k] = __float2bfloat16(a + b);
        Wcat[y * 1536 + k] = __float2bfloat16(a);
        Wcat[y * 1536 + H + k] = __float2bfloat16(b);
        if (bx == 0 && threadIdx.x == 0) bias[y] = bih[y] + bhh[y];
    } else if (y < 3152) {
        int r = y - 3072;
        Wp[r * H + k] = (r < 72) ? __float2bfloat16(Wpost[r * H + k])
                                 : __float2bfloat16(0.0f);
    } else if (y < 3408) {
        int b = y - 3152;
        A0[b * 1536 + k] = __float2bfloat16(src[(b * 16 + 15) * H + k]);  // src[:, -1]
        A0[b * 1536 + H + k] = __float2bfloat16(h0[b * H + k]);
    } else {
        if (bx == 0) flags[(y - 3408) * 256 + threadIdx.x] = 0u;
    }
}

// ---------------- persistent recurrence: steps 0..99 ----------------
// grid 256 blocks (16 mtg x 16 jg) x 768 threads (12 waves = 3 jt x 4 gates).
// Weight slice (Wc) pinned in regs via inline-asm loads. Step 0 streams Wcat.
// h via AGENT-scope relaxed atomics (LLC-coherent).
// Sync: flags[t][mtg][jg]; each producer block's 6 cell-store waves each
// drain own stores and atomicAdd +1 -> word reaches 6 when h is visible.
// Consumer: wave 0 only, 16 lanes watch the 16 words, ballot, barrier release.
#define FLAG_DONE 6u
#define LDS_H_STRIDE  776    // t>=1: 768 + 8 shorts
#define LDS_T0_STRIDE 1544   // t==0: 1536 + 8 shorts
#define XCH_STRIDE    17     // 16 + 1 pad floats

#define LDW(nm, idx) \
    asm volatile("global_load_dwordx4 %0, %1, off" \
                 : "=v"(nm) : "v"(wptr + (idx) * 32))

#define KSTEP(nm, idx) { \
    short8 a_ = *(const short8*)(&lds_h[col * LDS_H_STRIDE + (idx) * 32 + quad * 8]); \
    acc = __builtin_amdgcn_mfma_f32_16x16x32_bf16(a_, nm, acc, 0, 0, 0); }

__global__ __launch_bounds__(768, 3) void lstm_persist(
    const __hip_bfloat16* __restrict__ Wc,    // 3072 x 768 bf16 (Wih+Whh)
    const __hip_bfloat16* __restrict__ Wcat,  // 3072 x 1536 bf16 [Wih|Whh]
    const float* __restrict__ bias,           // 3072
    const float* __restrict__ c0in,           // B x H fp32 (c0 input)
    const __hip_bfloat16* __restrict__ A0,    // 256 x 1536 [x0|h0]
    __hip_bfloat16* outs,                     // T x B x H bf16
    unsigned* flags)                          // 100 x 16 x 16 (zeroed)
{
    const int mtg  = blockIdx.x >> 4;    // batch group 0..15 (16 batches)
    const int jg   = blockIdx.x & 15;    // j group 0..15 (48 j values)
    const int tid  = threadIdx.x;
    const int lane = tid & 63;
    const int wave = tid >> 6;           // 0..11
    const int col  = lane & 15;
    const int quad = lane >> 4;
    const int jt_l = wave >> 2;          // 0..2  local j-tile
    const int gate = wave & 3;           // 0..3  (i,f,g,o)
    const int j    = jg * 48 + jt_l * 16 + col;   // this wave's j column

    __shared__ short lds_h[16 * LDS_T0_STRIDE];   // 49408 B (t0 tile; t>=1 stride 776)
    __shared__ float xch[12 * 16 * XCH_STRIDE];   // 13056 B gate exchange

    // ---- pin resident weight slice (Wc) in regs: 24 x short8 ----
    const short* wptr = (const short*)Wc + (size_t)(gate * H + j) * H + quad * 8;
    short8 w00,w01,w02,w03,w04,w05,w06,w07,w08,w09,w10,w11,
           w12,w13,w14,w15,w16,w17,w18,w19,w20,w21,w22,w23;
    LDW(w00,0);  LDW(w01,1);  LDW(w02,2);  LDW(w03,3);
    LDW(w04,4);  LDW(w05,5);  LDW(w06,6);  LDW(w07,7);
    LDW(w08,8);  LDW(w09,9);  LDW(w10,10); LDW(w11,11);
    LDW(w12,12); LDW(w13,13); LDW(w14,14); LDW(w15,15);
    LDW(w16,16); LDW(w17,17); LDW(w18,18); LDW(w19,19);
    LDW(w20,20); LDW(w21,21); LDW(w22,22); LDW(w23,23);
    asm volatile("s_waitcnt vmcnt(0)" ::: "memory");

    // ---- cell-role state (threads 0..383: two adjacent-j cells each) ----
    const int p    = tid;                 // pair id if < 384 (waves 0..5)
    const int bb   = p / 24;              // local batch 0..15
    const int jp   = p % 24;
    const int jloc = jp * 2;              // local j 0..46 (even)
    const int cjt  = jloc >> 4;           // j-tile of the pair
    const int jcol = jloc & 15;
    const int bglob = mtg * 16 + bb;
    const int jglob = jg * 48 + jloc;
    float c0v = 0.f, c1v = 0.f;
    float bi0=0,bi1=0,bf0=0,bf1=0,bg0=0,bg1=0,bo0=0,bo1=0;
    if (p < 384) {
        c0v = c0in[(size_t)bglob * H + jglob];
        c1v = c0in[(size_t)bglob * H + jglob + 1];
        bi0 = bias[0*H + jglob]; bi1 = bias[0*H + jglob + 1];
        bf0 = bias[1*H + jglob]; bf1 = bias[1*H + jglob + 1];
        bg0 = bias[2*H + jglob]; bg1 = bias[2*H + jglob + 1];
        bo0 = bias[3*H + jglob]; bo1 = bias[3*H + jglob + 1];
    }

    const short* outs_s = (const short*)outs;

    for (int t = 0; t < T; ++t) {
        f32x4 acc = {0.f, 0.f, 0.f, 0.f};

        if (t == 0) {
            // ---- stage A0[16 rows][1536] -> LDS (plain loads; prior kernel) ----
            const u64* a8 = (const u64*)((const short*)A0 + (size_t)(mtg * 16) * 1536);
#pragma unroll
            for (int i = 0; i < 8; ++i) {
                int idx = tid + i * 768;      // 0..6143 (16 rows x 384 u64)
                int br  = idx / 384;
                int ch  = idx % 384;
                *(u64*)&lds_h[br * LDS_T0_STRIDE + ch * 4] = a8[(size_t)br * 384 + ch];
            }
            __syncthreads();   // (B)

            // ---- K=1536 GEMM streaming Wcat (one-time) ----
            const short* wq = (const short*)Wcat + (size_t)(gate * H + j) * 1536 + quad * 8;
            for (int kk = 0; kk < 48; ++kk) {
                short8 a_ = *(const short8*)(&lds_h[col * LDS_T0_STRIDE + kk * 32 + quad * 8]);
                short8 b_ = *(const short8*)(wq + kk * 32);
                acc = __builtin_amdgcn_mfma_f32_16x16x32_bf16(a_, b_, acc, 0, 0, 0);
            }
        } else {
            // ---- wave 0 only: 16 lanes watch the 16 producer flag words ----
            if (wave == 0) {
                const unsigned* fl = &flags[((unsigned)(t - 1) * 16u + (unsigned)mtg) * 16u];
                unsigned v;
                int guard = 0;
                do {
                    v = (lane < 16) ? __hip_atomic_load(&fl[lane], __ATOMIC_RELAXED,
                                                        __HIP_MEMORY_SCOPE_AGENT)
                                    : FLAG_DONE;
                } while (__ballot(v < FLAG_DONE) != 0ull && ++guard < (1 << 24));
            }
            __syncthreads();   // (A) release block

            // ---- stage h(t-1)[16 rows][768] -> LDS via LLC-coherent 8B loads ----
            const u64* hsrc8 = (const u64*)(outs_s + (size_t)(t - 1) * B * H
                                                   + (size_t)mtg * 16 * H);
#pragma unroll
            for (int i = 0; i < 4; ++i) {
                int idx = tid + i * 768;      // 0..3071 (16 rows x 192 u64)
                int br  = idx / 192;
                int ch  = idx % 192;
                u64 v8 = __hip_atomic_load(&hsrc8[br * 192 + ch],
                                           __ATOMIC_RELAXED, __HIP_MEMORY_SCOPE_AGENT);
                *(u64*)&lds_h[br * LDS_H_STRIDE + ch * 4] = v8;
            }
            __syncthreads();   // (B)

            // ---- K=768 GEMM vs pinned weights ----
            KSTEP(w00,0)  KSTEP(w01,1)  KSTEP(w02,2)  KSTEP(w03,3)
            KSTEP(w04,4)  KSTEP(w05,5)  KSTEP(w06,6)  KSTEP(w07,7)
            KSTEP(w08,8)  KSTEP(w09,9)  KSTEP(w10,10) KSTEP(w11,11)
            KSTEP(w12,12) KSTEP(w13,13) KSTEP(w14,14) KSTEP(w15,15)
            KSTEP(w16,16) KSTEP(w17,17) KSTEP(w18,18) KSTEP(w19,19)
            KSTEP(w20,20) KSTEP(w21,21) KSTEP(w22,22) KSTEP(w23,23)
        }

        // ---- exchange gate tiles through LDS ----
        float* xw = &xch[(size_t)wave * 16 * XCH_STRIDE];
#pragma unroll
        for (int r = 0; r < 4; ++r)
            xw[(quad * 4 + r) * XCH_STRIDE + col] = acc[r];
        __syncthreads();   // (C) xch ready; also orders lds_h reads vs next staging

        // ---- cell update + per-wave publish: waves 0..5 ----
        if (p < 384) {
            const float* xg = &xch[(size_t)(cjt * 4) * 16 * XCH_STRIDE + bb * XCH_STRIDE + jcol];
            const int gs = 16 * XCH_STRIDE;
            float i0 = xg[0*gs] + bi0, i1 = xg[0*gs + 1] + bi1;
            float f0 = xg[1*gs] + bf0, f1 = xg[1*gs + 1] + bf1;
            float g0 = xg[2*gs] + bg0, g1 = xg[2*gs + 1] + bg1;
            float o0 = xg[3*gs] + bo0, o1 = xg[3*gs + 1] + bo1;
            float cn0 = sigm(f0) * c0v + sigm(i0) * tanh_fast(g0);
            float cn1 = sigm(f1) * c1v + sigm(i1) * tanh_fast(g1);
            c0v = cn0; c1v = cn1;
            __hip_bfloat16 h0b = __float2bfloat16(sigm(o0) * tanh_fast(cn0));
            __hip_bfloat16 h1b = __float2bfloat16(sigm(o1) * tanh_fast(cn1));
            unsigned u = (unsigned)(*(unsigned short*)&h0b)
                       | ((unsigned)(*(unsigned short*)&h1b) << 16);
            unsigned* dst = (unsigned*)(outs_s + (size_t)t * B * H
                                               + (size_t)bglob * H + jglob);
            __hip_atomic_store(dst, u, __ATOMIC_RELAXED, __HIP_MEMORY_SCOPE_AGENT);

            // this wave's stores are at LLC -> bump the step-t flag by 1 (of 6)
            asm volatile("s_waitcnt vmcnt(0)" ::: "memory");
            if (lane == 0)
                atomicAdd(&flags[((unsigned)t * 16u + (unsigned)mtg) * 16u + jg], 1u);
        }
    }
}

// ---------------- post projection ----------------
__global__ __launch_bounds__(64) void proj(
    const __hip_bfloat16* __restrict__ Hs,   // T x B x H
    const __hip_bfloat16* __restrict__ Wp,   // 80 x H (padded bf16)
    const float* __restrict__ bpost,         // 72
    float* __restrict__ out)                 // B x T x 72
{
    const int mt = blockIdx.x;
    const int lane = threadIdx.x;
    const int col = lane & 15;
    const int quad = lane >> 4;

    const short* Ap = (const short*)Hs + (size_t)(mt * 16 + col) * H + quad * 8;
    const short* Wb = (const short*)Wp;

    f32x4 acc[5];
#pragma unroll
    for (int nt = 0; nt < 5; ++nt) acc[nt] = (f32x4){0.f, 0.f, 0.f, 0.f};

    for (int k = 0; k < H; k += 32) {
        short8 a = *(const short8*)(Ap + k);
#pragma unroll
        for (int nt = 0; nt < 5; ++nt) {
            short8 b = *(const short8*)(Wb + (size_t)(nt * 16 + col) * H + quad * 8 + k);
            acc[nt] = __builtin_amdgcn_mfma_f32_16x16x32_bf16(a, b, acc[nt], 0, 0, 0);
        }
    }

#pragma unroll
    for (int nt = 0; nt < 5; ++nt) {
        const int o = nt * 16 + col;
        if (o < 72) {
            const float bb = bpost[o];
#pragma unroll
            for (int r = 0; r < 4; ++r) {
                const int m = mt * 16 + quad * 4 + r;
                const int t = m >> 8;
                const int b = m & 255;
                out[((size_t)b * T + t) * 72 + o] = acc[nt][r] + bb;
            }
        }
    }
}

// ---------------- launch ----------------

extern "C" void kernel_launch(void* const* d_in, const int* in_sizes, int n_in,
                              void* d_out, int out_size, void* d_ws, size_t ws_size,
                              hipStream_t stream) {
    const float* src   = (const float*)d_in[0];
    const float* h0    = (const float*)d_in[2];
    const float* c0    = (const float*)d_in[3];
    const float* Wih   = (const float*)d_in[4];
    const float* Whh   = (const float*)d_in[5];
    const float* bih   = (const float*)d_in[6];
    const float* bhh   = (const float*)d_in[7];
    const float* Wpost = (const float*)d_in[8];
    const float* bpost = (const float*)d_in[9];
    float* out = (float*)d_out;

    char* ws = (char*)d_ws;
    __hip_bfloat16* Wcat  = (__hip_bfloat16*)(ws + 0);          //  9,437,184 B
    __hip_bfloat16* Wc    = (__hip_bfloat16*)(ws + 9437184);    //  4,718,592 B
    float*          bias  = (float*)(ws + 14155776);            //     12,288 B
    __hip_bfloat16* Wp    = (__hip_bfloat16*)(ws + 14168064);   //    122,880 B
    __hip_bfloat16* A0    = (__hip_bfloat16*)(ws + 14290944);   //    786,432 B
    __hip_bfloat16* outs  = (__hip_bfloat16*)(ws + 15863808);   // 39,321,600 B
    unsigned*       flags = (unsigned*)(ws + 55185408);         //    102,400 B

    // all prep in one dispatch
    prep_all<<<dim3(3, 3508), 256, 0, stream>>>(src, h0, Wih, Whh, bih, bhh, Wpost,
                                                Wc, Wcat, bias, Wp, A0, flags);

    // steps 0..99 in one persistent kernel (step 0 folded in)
    lstm_persist<<<256, 768, 0, stream>>>(Wc, Wcat, bias, c0, A0, outs, flags);

    proj<<<1600, 64, 0, stream>>>(outs, Wp, bpost, out);
}

// Round 9
// 500.205 us; speedup vs baseline: 1.7270x; 1.7270x over previous
//
#include <hip/hip_runtime.h>
#include <hip/hip_bf16.h>
#include <math.h>

#define H 768
#define B 256
#define T 100

typedef __attribute__((ext_vector_type(8))) short short8;
typedef __attribute__((ext_vector_type(4))) float f32x4;
typedef unsigned long long u64;

static __device__ __forceinline__ float sigm(float x) {
    return 1.0f / (1.0f + __expf(-x));
}
static __device__ __forceinline__ float tanh_fast(float x) {
    return 1.0f - 2.0f / (__expf(2.0f * x) + 1.0f);
}

// ---------------- fused prep (single dispatch) ----------------
// grid dim3(3, 9808), block 256:
//   y <  3072 : weight row y  (Wc, Wcat, bias)
//   y <  3152 : Wp row (y-3072), zero-padded beyond 72
//   y <  3408 : A0 batch row (y-3152)
//   y <  9808 : sig zero chunk (y-3408): 6400 rows x 768 u64 = 39.3 MB
__global__ void prep_all(const float* __restrict__ src, const float* __restrict__ h0,
                         const float* __restrict__ Wih, const float* __restrict__ Whh,
                         const float* __restrict__ bih, const float* __restrict__ bhh,
                         const float* __restrict__ Wpost,
                         __hip_bfloat16* __restrict__ Wc,    // 3072 x 768 (Wih+Whh)
                         __hip_bfloat16* __restrict__ Wcat,  // 3072 x 1536 [Wih|Whh]
                         float* __restrict__ bias,           // 3072
                         __hip_bfloat16* __restrict__ Wp,    // 80 x 768
                         __hip_bfloat16* __restrict__ A0,    // 256 x 1536 [x0|h0]
                         u64* __restrict__ sig64)            // T*B*192 u64, zeroed
{
    const int bx = blockIdx.x;
    const int y  = blockIdx.y;
    const int k  = bx * 256 + threadIdx.x;
    if (y < 3072) {
        float a = Wih[y * H + k];
        float b = Whh[y * H + k];
        Wc[y * H + k] = __float2bfloat16(a + b);
        Wcat[y * 1536 + k] = __float2bfloat16(a);
        Wcat[y * 1536 + H + k] = __float2bfloat16(b);
        if (bx == 0 && threadIdx.x == 0) bias[y] = bih[y] + bhh[y];
    } else if (y < 3152) {
        int r = y - 3072;
        Wp[r * H + k] = (r < 72) ? __float2bfloat16(Wpost[r * H + k])
                                 : __float2bfloat16(0.0f);
    } else if (y < 3408) {
        int b = y - 3152;
        A0[b * 1536 + k] = __float2bfloat16(src[(b * 16 + 15) * H + k]);  // src[:, -1]
        A0[b * 1536 + H + k] = __float2bfloat16(h0[b * H + k]);
    } else {
        sig64[(size_t)(y - 3408) * 768 + k] = 0ull;
    }
}

// ---------------- persistent recurrence: steps 0..99 ----------------
// grid 256 blocks (16 mtg x 16 jg) x 768 threads (12 waves = 3 jt x 4 gates).
// One gate per wave: 24 pinned short8 (96 regs) via inline-asm (R5-proven).
// Sync: data-is-signal. h stored as ~bf16 (nonzero) into pre-zeroed sig via
// agent-scope relaxed stores; consumers poll their own staging words until
// all 16-bit fields are nonzero, then un-invert into LDS. No flags/counters.
#define LDS_H_STRIDE  772    // shorts; 386 dwords (=2 mod 32: uniform 4-way), 8B-aligned rows
#define LDS_T0_STRIDE 1540   // shorts; 770 dwords, 8B-aligned rows
#define XCH_STRIDE    17     // 16 + 1 pad floats

#define LDW(nm, idx) \
    asm volatile("global_load_dwordx4 %0, %1, off" \
                 : "=v"(nm) : "v"(wptr + (idx) * 32))

#define KSTEP(nm, idx) { \
    short8 a_ = *(const short8*)(&lds_h[col * LDS_H_STRIDE + (idx) * 32 + quad * 8]); \
    acc = __builtin_amdgcn_mfma_f32_16x16x32_bf16(a_, nm, acc, 0, 0, 0); }

static __device__ __forceinline__ bool sig_ok(u64 x) {
    return (unsigned short)x && (unsigned short)(x >> 16) &&
           (unsigned short)(x >> 32) && (unsigned short)(x >> 48);
}

__global__ __launch_bounds__(768, 3) void lstm_persist(
    const __hip_bfloat16* __restrict__ Wc,    // 3072 x 768 bf16 (Wih+Whh)
    const __hip_bfloat16* __restrict__ Wcat,  // 3072 x 1536 bf16 [Wih|Whh]
    const float* __restrict__ bias,           // 3072
    const float* __restrict__ c0in,           // B x H fp32
    const __hip_bfloat16* __restrict__ A0,    // 256 x 1536 [x0|h0]
    unsigned* sig)                            // T x B x 384 u32 (~bf16 pairs), zeroed
{
    const int mtg  = blockIdx.x >> 4;    // batch group 0..15 (16 batches)
    const int jg   = blockIdx.x & 15;    // j group 0..15 (48 j values)
    const int tid  = threadIdx.x;
    const int lane = tid & 63;
    const int wave = tid >> 6;           // 0..11
    const int col  = lane & 15;
    const int quad = lane >> 4;
    const int jt_l = wave >> 2;          // 0..2  local j-tile
    const int gate = wave & 3;           // 0..3  (i,f,g,o)
    const int j    = jg * 48 + jt_l * 16 + col;   // this wave's j column

    __shared__ short lds_h[16 * LDS_T0_STRIDE];   // 49280 B (t0 tile; t>=1 stride 772)
    __shared__ float xch[12 * 16 * XCH_STRIDE];   // 13056 B gate exchange

    // ---- pin resident weight slice (Wc) in regs: 24 x short8 (R5-proven) ----
    const short* wptr = (const short*)Wc + (size_t)(gate * H + j) * H + quad * 8;
    short8 w00,w01,w02,w03,w04,w05,w06,w07,w08,w09,w10,w11,
           w12,w13,w14,w15,w16,w17,w18,w19,w20,w21,w22,w23;
    LDW(w00,0);  LDW(w01,1);  LDW(w02,2);  LDW(w03,3);
    LDW(w04,4);  LDW(w05,5);  LDW(w06,6);  LDW(w07,7);
    LDW(w08,8);  LDW(w09,9);  LDW(w10,10); LDW(w11,11);
    LDW(w12,12); LDW(w13,13); LDW(w14,14); LDW(w15,15);
    LDW(w16,16); LDW(w17,17); LDW(w18,18); LDW(w19,19);
    LDW(w20,20); LDW(w21,21); LDW(w22,22); LDW(w23,23);
    asm volatile("s_waitcnt vmcnt(0)" ::: "memory");

    // ---- cell-role state (threads 0..383: two adjacent-j cells each) ----
    const int p    = tid;                 // pair id if < 384 (waves 0..5)
    const int bb   = p / 24;              // local batch 0..15
    const int jp   = p % 24;
    const int jloc = jp * 2;              // local j 0..46 (even)
    const int cjt  = jloc >> 4;           // j-tile of the pair
    const int jcol = jloc & 15;
    const int bglob = mtg * 16 + bb;
    const int jglob = jg * 48 + jloc;
    float c0v = 0.f, c1v = 0.f;
    float bi0=0,bi1=0,bf0=0,bf1=0,bg0=0,bg1=0,bo0=0,bo1=0;
    if (p < 384) {
        c0v = c0in[(size_t)bglob * H + jglob];
        c1v = c0in[(size_t)bglob * H + jglob + 1];
        bi0 = bias[0*H + jglob]; bi1 = bias[0*H + jglob + 1];
        bf0 = bias[1*H + jglob]; bf1 = bias[1*H + jglob + 1];
        bg0 = bias[2*H + jglob]; bg1 = bias[2*H + jglob + 1];
        bo0 = bias[3*H + jglob]; bo1 = bias[3*H + jglob + 1];
    }

    const u64* sig64c = (const u64*)sig;
    const int r0  = tid / 192;    // staging row base 0..3
    const int wrd = tid % 192;    // u64 word within row

    for (int t = 0; t < T; ++t) {
        f32x4 acc = {0.f, 0.f, 0.f, 0.f};

        if (t == 0) {
            // ---- stage A0[16 rows][1536] -> LDS (plain loads; prior kernel) ----
            const u64* a8 = (const u64*)((const short*)A0 + (size_t)(mtg * 16) * 1536);
#pragma unroll
            for (int i = 0; i < 8; ++i) {
                int idx = tid + i * 768;      // 0..6143 (16 rows x 384 u64)
                int br  = idx / 384;
                int ch  = idx % 384;
                *(u64*)&lds_h[br * LDS_T0_STRIDE + ch * 4] = a8[(size_t)br * 384 + ch];
            }
            __syncthreads();   // (B)

            // ---- K=1536 GEMM streaming Wcat (one-time) ----
            const short* wq = (const short*)Wcat + (size_t)(gate * H + j) * 1536 + quad * 8;
            for (int kk = 0; kk < 48; ++kk) {
                short8 a_ = *(const short8*)(&lds_h[col * LDS_T0_STRIDE + kk * 32 + quad * 8]);
                short8 b_ = *(const short8*)(wq + kk * 32);
                acc = __builtin_amdgcn_mfma_f32_16x16x32_bf16(a_, b_, acc, 0, 0, 0);
            }
        } else {
            // ---- poll+stage h(t-1): each thread owns 4 u64 words; data IS signal ----
            const u64* hb = sig64c + ((size_t)(t - 1) * B + (size_t)(mtg * 16)) * 192;
            unsigned pending = 0xFu;
#pragma unroll
            for (int i = 0; i < 4; ++i) {
                int row = r0 + 4 * i;
                u64 x = __hip_atomic_load(hb + (size_t)row * 192 + wrd,
                                          __ATOMIC_RELAXED, __HIP_MEMORY_SCOPE_AGENT);
                if (sig_ok(x)) {
                    *(u64*)&lds_h[row * LDS_H_STRIDE + wrd * 4] = ~x;
                    pending &= ~(1u << i);
                }
            }
            int guard = 0;
            while (pending && ++guard < (1 << 22)) {
                __builtin_amdgcn_s_sleep(1);
#pragma unroll
                for (int i = 0; i < 4; ++i) {
                    if (pending & (1u << i)) {
                        int row = r0 + 4 * i;
                        u64 x = __hip_atomic_load(hb + (size_t)row * 192 + wrd,
                                                  __ATOMIC_RELAXED, __HIP_MEMORY_SCOPE_AGENT);
                        if (sig_ok(x)) {
                            *(u64*)&lds_h[row * LDS_H_STRIDE + wrd * 4] = ~x;
                            pending &= ~(1u << i);
                        }
                    }
                }
            }
            __syncthreads();   // (B) lds_h ready

            // ---- K=768 GEMM vs pinned weights ----
            KSTEP(w00,0)  KSTEP(w01,1)  KSTEP(w02,2)  KSTEP(w03,3)
            KSTEP(w04,4)  KSTEP(w05,5)  KSTEP(w06,6)  KSTEP(w07,7)
            KSTEP(w08,8)  KSTEP(w09,9)  KSTEP(w10,10) KSTEP(w11,11)
            KSTEP(w12,12) KSTEP(w13,13) KSTEP(w14,14) KSTEP(w15,15)
            KSTEP(w16,16) KSTEP(w17,17) KSTEP(w18,18) KSTEP(w19,19)
            KSTEP(w20,20) KSTEP(w21,21) KSTEP(w22,22) KSTEP(w23,23)
        }

        // ---- exchange gate tiles through LDS ----
        float* xw = &xch[(size_t)wave * 16 * XCH_STRIDE];
#pragma unroll
        for (int r = 0; r < 4; ++r)
            xw[(quad * 4 + r) * XCH_STRIDE + col] = acc[r];
        __syncthreads();   // (C) xch ready; lds_h reads of this step all done

        // ---- cell update + inverted-bf16 publish (store IS the signal) ----
        if (p < 384) {
            const float* xg = &xch[(size_t)(cjt * 4) * 16 * XCH_STRIDE + bb * XCH_STRIDE + jcol];
            const int gs = 16 * XCH_STRIDE;
            float i0 = xg[0*gs] + bi0, i1 = xg[0*gs + 1] + bi1;
            float f0 = xg[1*gs] + bf0, f1 = xg[1*gs + 1] + bf1;
            float g0 = xg[2*gs] + bg0, g1 = xg[2*gs + 1] + bg1;
            float o0 = xg[3*gs] + bo0, o1 = xg[3*gs + 1] + bo1;
            float cn0 = sigm(f0) * c0v + sigm(i0) * tanh_fast(g0);
            float cn1 = sigm(f1) * c1v + sigm(i1) * tanh_fast(g1);
            c0v = cn0; c1v = cn1;
            __hip_bfloat16 h0b = __float2bfloat16(sigm(o0) * tanh_fast(cn0));
            __hip_bfloat16 h1b = __float2bfloat16(sigm(o1) * tanh_fast(cn1));
            unsigned lo = (unsigned)(unsigned short)~(*(unsigned short*)&h0b);  // nonzero
            unsigned hi = (unsigned)(unsigned short)~(*(unsigned short*)&h1b);  // nonzero
            __hip_atomic_store(&sig[((size_t)t * B + bglob) * 384 + (jglob >> 1)],
                               lo | (hi << 16),
                               __ATOMIC_RELAXED, __HIP_MEMORY_SCOPE_AGENT);
        }

        __syncthreads();   // (D) WAR: xch/lds_h consumed before next step overwrites
    }
}

// ---------------- post projection (reads inverted sig) ----------------
__global__ __launch_bounds__(64) void proj(
    const short* __restrict__ Hs,            // (T*B) x 768 inverted bf16
    const __hip_bfloat16* __restrict__ Wp,   // 80 x H (padded bf16)
    const float* __restrict__ bpost,         // 72
    float* __restrict__ out)                 // B x T x 72
{
    const int mt = blockIdx.x;
    const int lane = threadIdx.x;
    const int col = lane & 15;
    const int quad = lane >> 4;

    const short* Ap = Hs + (size_t)(mt * 16 + col) * H + quad * 8;
    const short* Wb = (const short*)Wp;

    f32x4 acc[5];
#pragma unroll
    for (int nt = 0; nt < 5; ++nt) acc[nt] = (f32x4){0.f, 0.f, 0.f, 0.f};

    for (int k = 0; k < H; k += 32) {
        short8 a = ~(*(const short8*)(Ap + k));   // un-invert
#pragma unroll
        for (int nt = 0; nt < 5; ++nt) {
            short8 b = *(const short8*)(Wb + (size_t)(nt * 16 + col) * H + quad * 8 + k);
            acc[nt] = __builtin_amdgcn_mfma_f32_16x16x32_bf16(a, b, acc[nt], 0, 0, 0);
        }
    }

#pragma unroll
    for (int nt = 0; nt < 5; ++nt) {
        const int o = nt * 16 + col;
        if (o < 72) {
            const float bb = bpost[o];
#pragma unroll
            for (int r = 0; r < 4; ++r) {
                const int m = mt * 16 + quad * 4 + r;
                const int t = m >> 8;        // row = t*256 + b
                const int b = m & 255;
                out[((size_t)b * T + t) * 72 + o] = acc[nt][r] + bb;
            }
        }
    }
}

// ---------------- launch ----------------

extern "C" void kernel_launch(void* const* d_in, const int* in_sizes, int n_in,
                              void* d_out, int out_size, void* d_ws, size_t ws_size,
                              hipStream_t stream) {
    const float* src   = (const float*)d_in[0];
    const float* h0    = (const float*)d_in[2];
    const float* c0    = (const float*)d_in[3];
    const float* Wih   = (const float*)d_in[4];
    const float* Whh   = (const float*)d_in[5];
    const float* bih   = (const float*)d_in[6];
    const float* bhh   = (const float*)d_in[7];
    const float* Wpost = (const float*)d_in[8];
    const float* bpost = (const float*)d_in[9];
    float* out = (float*)d_out;

    char* ws = (char*)d_ws;
    __hip_bfloat16* Wcat = (__hip_bfloat16*)(ws + 0);          //  9,437,184 B
    __hip_bfloat16* Wc   = (__hip_bfloat16*)(ws + 9437184);    //  4,718,592 B
    float*          bias = (float*)(ws + 14155776);            //     12,288 B
    __hip_bfloat16* Wp   = (__hip_bfloat16*)(ws + 14168064);   //    122,880 B
    __hip_bfloat16* A0   = (__hip_bfloat16*)(ws + 14290944);   //    786,432 B
    unsigned*       sig  = (unsigned*)(ws + 15863808);         // 39,321,600 B

    // all prep (weights, Wp, A0, sig zero) in one dispatch
    prep_all<<<dim3(3, 9808), 256, 0, stream>>>(src, h0, Wih, Whh, bih, bhh, Wpost,
                                                Wc, Wcat, bias, Wp, A0, (u64*)sig);

    // steps 0..99 in one persistent kernel (data-is-signal sync)
    lstm_persist<<<256, 768, 0, stream>>>(Wc, Wcat, bias, c0, A0, sig);

    proj<<<1600, 64, 0, stream>>>((const short*)sig, Wp, bpost, out);
}